// Round 3
// baseline (250.910 us; speedup 1.0000x reference)
//
#include <hip/hip_runtime.h>
#include <hip/hip_bf16.h>

#define NEG_SLOPE 0.2f
#define NBUCK 782      // ceil(100000 / 128) buckets of 128 dst nodes
#define ABLK 8192      // edges per bucket_edges block
#define CAP 3072       // max edges per bucket (mean 2048, sd ~45 -> +22 sigma)

typedef __attribute__((ext_vector_type(8))) short bf16x8v;
typedef __attribute__((ext_vector_type(4))) float f32x4;
typedef __attribute__((ext_vector_type(2))) float f32x2;

__device__ __forceinline__ unsigned f2bf_bits(float f) {
    unsigned u = __float_as_uint(f);
    return (u + 0x7fffu + ((u >> 16) & 1u)) >> 16;   // RNE fp32 -> bf16 bits
}
__device__ __forceinline__ float bflo(unsigned u) { return __uint_as_float(u << 16); }
__device__ __forceinline__ float bfhi(unsigned u) { return __uint_as_float(u & 0xffff0000u); }

// packed fp32 FMA: acc.{x,y} += x.{x,y} * w.{x,y}  (one VALU inst for 2 channels)
__device__ __forceinline__ void pkfma(f32x2& a, f32x2 x, f32x2 w) {
    asm("v_pk_fma_f32 %0, %1, %2, %0" : "+v"(a) : "v"(x), "v"(w));
}

// ---------------------------------------------------------------------------
// MFMA GEMM: [h | as | ad] = bf16(x) @ B[128,144], fp32 acc.
// Block: 256 thr = 4 waves, 64 rows. Wave: 16 rows x 144 cols = 9 MFMA tiles.
// ---------------------------------------------------------------------------
__global__ __launch_bounds__(256) void gemm_mfma(const float* __restrict__ x,
                                                 const short* __restrict__ WtE,
                                                 short* __restrict__ hout,
                                                 float* __restrict__ as,
                                                 float* __restrict__ ad, int N) {
    __shared__ short xs[64 * 136];
    __shared__ short wt[144 * 136];
    const int tid = threadIdx.x;
    const int r0 = blockIdx.x * 64;

#pragma unroll
    for (int p = 0; p < 9; ++p) {
        int idx = p * 256 + tid;           // 2304 chunks of 8 shorts
        int n = idx >> 4, kk = (idx & 15) * 8;
        *(uint4*)&wt[n * 136 + kk] = *(const uint4*)(WtE + n * 128 + kk);
    }
#pragma unroll
    for (int p = 0; p < 8; ++p) {
        int lin = p * 1024 + tid * 4;
        int row = lin >> 7, k = lin & 127;
        int gr = r0 + row;
        int grc = gr < N ? gr : N - 1;
        float4 v = *(const float4*)(x + (size_t)grc * 128 + k);
        unsigned p0 = f2bf_bits(v.x) | (f2bf_bits(v.y) << 16);
        unsigned p1 = f2bf_bits(v.z) | (f2bf_bits(v.w) << 16);
        *(uint2*)&xs[row * 136 + k] = make_uint2(p0, p1);
    }
    __syncthreads();

    const int wv = tid >> 6;
    const int lane = tid & 63;
    const int lc = lane & 15, quad = lane >> 4;
    f32x4 acc[9];
#pragma unroll
    for (int c = 0; c < 9; ++c) acc[c] = (f32x4){0.f, 0.f, 0.f, 0.f};
    const short* aB = &xs[(wv * 16 + lc) * 136 + quad * 8];
    const short* bB = &wt[lc * 136 + quad * 8];
#pragma unroll
    for (int kc = 0; kc < 4; ++kc) {
        bf16x8v af = *(const bf16x8v*)(aB + kc * 32);
#pragma unroll
        for (int c = 0; c < 9; ++c) {
            bf16x8v bf = *(const bf16x8v*)(bB + c * (16 * 136) + kc * 32);
            acc[c] = __builtin_amdgcn_mfma_f32_16x16x32_bf16(af, bf, acc[c], 0, 0, 0);
        }
    }

    const int rowb = r0 + wv * 16 + quad * 4;
#pragma unroll
    for (int c = 0; c < 8; ++c) {
#pragma unroll
        for (int r = 0; r < 4; ++r) {
            int row = rowb + r;
            if (row < N) hout[(size_t)row * 128 + c * 16 + lc] = (short)f2bf_bits(acc[c][r]);
        }
    }
    // alpha columns: lc<8 -> as head lc; lc>=8 -> ad head lc-8
#pragma unroll
    for (int r = 0; r < 4; ++r) {
        int row = rowb + r;
        if (row < N) {
            if (lc < 8) as[row * 8 + lc] = acc[8][r];
            else        ad[row * 8 + (lc - 8)] = acc[8][r];
        }
    }
}

// ---------------------------------------------------------------------------
// Phase A: bucket edges by dst>>7 into per-block slabs. Register staging,
// packed uint32 = src | (dst&127)<<17. Hierarchical shfl scan.
// Blocks [0,nblk): bucketing. Blocks [nblk, nblk+18): absorbed prep_w work.
// ---------------------------------------------------------------------------
__global__ __launch_bounds__(1024) void bucket_edges(const int* __restrict__ ei, int E,
                                                     int nblk,
                                                     unsigned* __restrict__ slab,
                                                     int2* __restrict__ csG,
                                                     const float* __restrict__ W,
                                                     const float* __restrict__ a_src,
                                                     const float* __restrict__ a_dst,
                                                     short* __restrict__ WtE) {
    const int t = threadIdx.x;
    const int blk = blockIdx.x;

    if (blk >= nblk) {            // ---- prep_w path: 18 blocks x 1024 = 18432
        int id = (blk - nblk) * 1024 + t;
        if (id < 144 * 128) {
            int n = id >> 7, k = id & 127;
            float v;
            if (n < 128) {
                v = W[k * 128 + n];
            } else if (n < 136) {
                int hh = n - 128; float s = 0.f;
#pragma unroll
                for (int d = 0; d < 16; ++d) s += W[k * 128 + hh * 16 + d] * a_src[hh * 16 + d];
                v = s;
            } else {
                int hh = n - 136; float s = 0.f;
#pragma unroll
                for (int d = 0; d < 16; ++d) s += W[k * 128 + hh * 16 + d] * a_dst[hh * 16 + d];
                v = s;
            }
            WtE[id] = (short)f2bf_bits(v);
        }
        return;
    }

    __shared__ int hist[1024];
    __shared__ int cur[NBUCK];
    __shared__ int wpart[16];
    const int base = blk * ABLK;
    int count = E - base; if (count > ABLK) count = ABLK;

    int sr[8], dr[8];
    hist[t] = 0;
#pragma unroll
    for (int k = 0; k < 8; ++k) {
        int i = k * 1024 + t;
        if (i < count) { sr[k] = ei[base + i]; dr[k] = ei[E + base + i]; }
    }
    __syncthreads();
#pragma unroll
    for (int k = 0; k < 8; ++k) {
        int i = k * 1024 + t;
        if (i < count) atomicAdd(&hist[dr[k] >> 7], 1);
    }
    __syncthreads();
    int v = hist[t];
    int lane = t & 63, wid = t >> 6;
    int sc = v;
#pragma unroll
    for (int off = 1; off < 64; off <<= 1) { int u = __shfl_up(sc, off); if (lane >= off) sc += u; }
    if (lane == 63) wpart[wid] = sc;
    __syncthreads();
    if (wid == 0 && lane < 16) {
        int wv = wpart[lane], wsum = wv;
#pragma unroll
        for (int off = 1; off < 16; off <<= 1) { int u = __shfl_up(wsum, off); if (lane >= off) wsum += u; }
        wpart[lane] = wsum - wv;
    }
    __syncthreads();
    int excl = sc - v + wpart[wid];
    if (t < NBUCK) {
        csG[(size_t)blk * NBUCK + t] = make_int2(v, excl);
        cur[t] = excl;
    }
    __syncthreads();
#pragma unroll
    for (int k = 0; k < 8; ++k) {
        int i = k * 1024 + t;
        if (i < count) {
            int d = dr[k];
            int pos = atomicAdd(&cur[d >> 7], 1);
            slab[(size_t)blk * ABLK + pos] = (unsigned)sr[k] | ((unsigned)(d & 127) << 17);
        }
    }
}

// ---------------------------------------------------------------------------
// Phase B: per bucket of 128 dst nodes. 8-lane-group-per-segment LDS gather,
// hist + scan -> rowS/rowE, scatter sortedSrc.
// NEW: exact degree-rank sort of the 128 nodes (descending, index tiebreak)
// -> nodeOrd, so aggregate waves get 8 degree-adjacent nodes (uniform loop
// trip counts, no predication waste).
// ---------------------------------------------------------------------------
__global__ __launch_bounds__(512) void build_csr(const unsigned* __restrict__ slab,
                                                 const int2* __restrict__ csG,
                                                 int nblk, int N,
                                                 int* __restrict__ rowS,
                                                 int* __restrict__ rowE,
                                                 int* __restrict__ sortedSrc,
                                                 int* __restrict__ nodeOrd) {
    __shared__ int eL[CAP];
    __shared__ int incl[512];
    __shared__ int cS[512];
    __shared__ int stS[512];
    __shared__ int lp[128];
    __shared__ int degS[128];
    __shared__ int rnk[128];
    __shared__ int wpart[8];
    __shared__ int halfSum;
    const int bb = blockIdx.x;
    const int t = threadIdx.x;
    const int nodeBase = bb << 7;
    const int bBase = bb * CAP;

    int c = 0, st = 0;
    if (t < nblk) { int2 cs = csG[(size_t)t * NBUCK + bb]; c = cs.x; st = cs.y; }
    cS[t] = c; stS[t] = st;
    if (t < 128) { lp[t] = 0; rnk[t] = 0; }
    int lane = t & 63, wid = t >> 6;
    int sc = c;
#pragma unroll
    for (int off = 1; off < 64; off <<= 1) { int u = __shfl_up(sc, off); if (lane >= off) sc += u; }
    if (lane == 63) wpart[wid] = sc;
    __syncthreads();
    if (wid == 0 && lane < 8) {
        int wv = wpart[lane], wsum = wv;
#pragma unroll
        for (int off = 1; off < 8; off <<= 1) { int u = __shfl_up(wsum, off); if (lane >= off) wsum += u; }
        wpart[lane] = wsum - wv;
    }
    __syncthreads();
    incl[t] = sc + wpart[wid];
    __syncthreads();
    int total = incl[511];
    if (total > CAP) total = CAP;   // statically impossible; guards LDS OOB
    // 8-lane-group-per-segment gather: group g handles segments g, g+64, ...
    {
        const int grp = t >> 3, li = t & 7;
        for (int s = grp; s < nblk; s += 64) {
            int cc = cS[s];
            int off0 = incl[s] - cc;
            const unsigned* p = slab + (size_t)s * ABLK + stS[s];
            for (int i = li; i < cc; i += 8) eL[off0 + i] = (int)p[i];
        }
    }
    __syncthreads();
    for (int e = t; e < total; e += 512) atomicAdd(&lp[((unsigned)eL[e]) >> 17], 1);
    __syncthreads();
    // scan 128 node counts
    int cnt = 0, s2 = 0;
    if (t < 128) {
        cnt = lp[t];
        degS[t] = cnt;
        s2 = cnt;
#pragma unroll
        for (int off = 1; off < 64; off <<= 1) { int u = __shfl_up(s2, off); if (lane >= off) s2 += u; }
        if (t == 63) halfSum = s2;
    }
    __syncthreads();
    if (t < 128) {
        int inc2 = s2 + (t >= 64 ? halfSum : 0);
        int ex = inc2 - cnt;
        int gn = nodeBase + t;
        if (gn < N) { rowS[gn] = bBase + ex; rowE[gn] = bBase + ex + cnt; }
        lp[t] = ex;
    }
    __syncthreads();
    // scatter edges into CSR windows
    for (int e = t; e < total; e += 512) {
        unsigned pk = (unsigned)eL[e];
        int pos = atomicAdd(&lp[pk >> 17], 1);
        sortedSrc[bBase + pos] = (int)(pk & 0x1FFFFu);
    }
    // exact degree-rank (descending, index tiebreak -> bijection).
    // thread t handles node t&127, comparison chunk (t>>7)*32..+32.
    {
        int n = t & 127, q = t >> 7;
        int dn = degS[n];
        int r = 0;
        int j0 = q * 32;
#pragma unroll
        for (int j = 0; j < 32; ++j) {
            int dj = degS[j0 + j];
            r += (dj > dn) || (dj == dn && (j0 + j) < n);
        }
        atomicAdd(&rnk[n], r);
    }
    __syncthreads();
    if (t < 128) nodeOrd[nodeBase + rnk[t]] = nodeBase + t;
}

// ---------------------------------------------------------------------------
// Aggregate v4: one wave = 8 nodes (degree-sorted ranks), one 8-lane group
// per node, lane = head p (16 channels via 2 uint4 loads).
//   * NO cross-lane reduction at all: each lane owns (node, head) acc + dsum.
//     (replaces 48 ds_swizzle + 51 VALU butterfly per node)
//   * prologue/self-loop/epilogue amortized over 8 nodes per wave.
//   * serial edge walk per group, 3-deep slot pipeline (24 gathers in
//     flight/wave); degree-sorted ranks keep loop trips wave-uniform.
// ---------------------------------------------------------------------------
__global__ __launch_bounds__(256, 6) void aggregate(const int* __restrict__ rowS,
                                                    const int* __restrict__ rowE,
                                                    const int* __restrict__ sortedSrc,
                                                    const int* __restrict__ nodeOrd,
                                                    const short* __restrict__ h,
                                                    const float* __restrict__ as,
                                                    const float* __restrict__ ad,
                                                    const float* __restrict__ bias,
                                                    float* __restrict__ out, int N) {
    const int lane = threadIdx.x & 63;
    const int wv = threadIdx.x >> 6;
    const int g = lane >> 3, p = lane & 7;
    const int slot = blockIdx.x * 32 + wv * 8 + g;   // grid covers NBUCK*128 slots
    const int node = nodeOrd[slot];
    const bool valid = node < N;                      // padded tail of last bucket
    int start = 0, end = 0;
    if (valid) { start = rowS[node]; end = rowE[node]; }
    const float adv = valid ? ad[node * 8 + p] : 0.f;
    const short* hb = h + p * 16;

    f32x2 acc[8];
#pragma unroll
    for (int k = 0; k < 8; ++k) acc[k] = (f32x2){0.f, 0.f};
    float dsum = 0.f;

    float as0 = 0.f, as1 = 0.f, as2 = 0.f;
    uint4 hA0 = {0,0,0,0}, hA1 = {0,0,0,0};
    uint4 hB0 = {0,0,0,0}, hB1 = {0,0,0,0};
    uint4 hC0 = {0,0,0,0}, hC1 = {0,0,0,0};

#define SLOT_LOAD(EV, ASV, H0, H1)                                  \
    if ((EV) < end) {                                               \
        int j = sortedSrc[EV];                                      \
        ASV = as[j * 8 + p];                                        \
        const uint4* hp = (const uint4*)(hb + (size_t)j * 128);     \
        H0 = hp[0]; H1 = hp[1];                                     \
    }

#define EDGE_COMPUTE(ASV, H0, H1)                                   \
    {                                                               \
        float tt = ASV + adv;                                       \
        tt = tt > 0.f ? tt : NEG_SLOPE * tt;                        \
        float w = __expf(tt);                                       \
        f32x2 wp = {w, w};                                          \
        f32x2 tv;                                                   \
        tv.x = bflo(H0.x); tv.y = bfhi(H0.x); pkfma(acc[0], tv, wp); \
        tv.x = bflo(H0.y); tv.y = bfhi(H0.y); pkfma(acc[1], tv, wp); \
        tv.x = bflo(H0.z); tv.y = bfhi(H0.z); pkfma(acc[2], tv, wp); \
        tv.x = bflo(H0.w); tv.y = bfhi(H0.w); pkfma(acc[3], tv, wp); \
        tv.x = bflo(H1.x); tv.y = bfhi(H1.x); pkfma(acc[4], tv, wp); \
        tv.x = bflo(H1.y); tv.y = bfhi(H1.y); pkfma(acc[5], tv, wp); \
        tv.x = bflo(H1.z); tv.y = bfhi(H1.z); pkfma(acc[6], tv, wp); \
        tv.x = bflo(H1.w); tv.y = bfhi(H1.w); pkfma(acc[7], tv, wp); \
        dsum += w;                                                  \
    }

    int e = start;
    SLOT_LOAD(e,     as0, hA0, hA1)
    SLOT_LOAD(e + 1, as1, hB0, hB1)
    SLOT_LOAD(e + 2, as2, hC0, hC1)

    while (e < end) {
        EDGE_COMPUTE(as0, hA0, hA1)
        SLOT_LOAD(e + 3, as0, hA0, hA1)
        if (e + 1 < end) EDGE_COMPUTE(as1, hB0, hB1)
        SLOT_LOAD(e + 4, as1, hB0, hB1)
        if (e + 2 < end) EDGE_COMPUTE(as2, hC0, hC1)
        SLOT_LOAD(e + 5, as2, hC0, hC1)
        e += 3;
    }

    // self-loop (each lane adds its head's self term once)
    if (valid) {
        float slas = as[node * 8 + p];
        const uint4* hp = (const uint4*)(hb + (size_t)node * 128);
        uint4 s0 = hp[0], s1 = hp[1];
        EDGE_COMPUTE(slas, s0, s1)

        float inv = 1.0f / (dsum + 1e-16f);
        float* op = out + (size_t)node * 128 + p * 16;
        const float* bp = bias + p * 16;
#pragma unroll
        for (int q = 0; q < 4; ++q) {
            float4 bv = *(const float4*)(bp + q * 4);
            float o0 = acc[2 * q].x     * inv + bv.x;
            float o1 = acc[2 * q].y     * inv + bv.y;
            float o2 = acc[2 * q + 1].x * inv + bv.z;
            float o3 = acc[2 * q + 1].y * inv + bv.w;
            o0 = o0 > 0.f ? o0 : 0.f; o1 = o1 > 0.f ? o1 : 0.f;
            o2 = o2 > 0.f ? o2 : 0.f; o3 = o3 > 0.f ? o3 : 0.f;
            *(float4*)(op + q * 4) = make_float4(o0, o1, o2, o3);
        }
    }
#undef SLOT_LOAD
#undef EDGE_COMPUTE
}

extern "C" void kernel_launch(void* const* d_in, const int* in_sizes, int n_in,
                              void* d_out, int out_size, void* d_ws, size_t ws_size,
                              hipStream_t stream) {
    const float* x     = (const float*)d_in[0];
    const int*   ei    = (const int*)d_in[1];
    const float* W     = (const float*)d_in[2];
    const float* a_src = (const float*)d_in[3];
    const float* a_dst = (const float*)d_in[4];
    const float* bias  = (const float*)d_in[5];
    float* out = (float*)d_out;

    const int N = in_sizes[0] / 128;   // 100000
    const int E = in_sizes[1] / 2;     // 1600000
    const int nblk = (E + ABLK - 1) / ABLK;  // 196

    char* ws = (char*)d_ws;
    size_t off = 0;
    auto alloc = [&](size_t bytes) { void* p = ws + off; off = (off + bytes + 255) & ~(size_t)255; return p; };
    short*    h         = (short*)alloc((size_t)N * 128 * 2);
    float*    as        = (float*)alloc((size_t)N * 8 * 4);
    float*    ad        = (float*)alloc((size_t)N * 8 * 4);
    unsigned* slab      = (unsigned*)alloc((size_t)nblk * ABLK * 4);
    int2*     csG       = (int2*)alloc((size_t)nblk * NBUCK * 8);
    int*      sortedSrc = (int*)alloc((size_t)NBUCK * CAP * 4);
    int*      rowS      = (int*)alloc((size_t)N * 4);
    int*      rowE      = (int*)alloc((size_t)N * 4);
    int*      nodeOrd   = (int*)alloc((size_t)NBUCK * 128 * 4);
    short*    WtE       = (short*)alloc((size_t)144 * 128 * 2);

    bucket_edges<<<nblk + 18, 1024, 0, stream>>>(ei, E, nblk, slab, csG, W, a_src, a_dst, WtE);
    gemm_mfma<<<(N + 63) / 64, 256, 0, stream>>>(x, WtE, h, as, ad, N);
    build_csr<<<NBUCK, 512, 0, stream>>>(slab, csG, nblk, N, rowS, rowE, sortedSrc, nodeOrd);
    aggregate<<<(NBUCK * 128) / 32, 256, 0, stream>>>(rowS, rowE, sortedSrc, nodeOrd, h, as, ad, bias, out, N);
}

// Round 4
// 222.007 us; speedup vs baseline: 1.1302x; 1.1302x over previous
//
#include <hip/hip_runtime.h>
#include <hip/hip_bf16.h>

#define NEG_SLOPE 0.2f
#define NBUCK 782      // ceil(100000 / 128) buckets of 128 dst nodes
#define ABLK 8192      // edges per bucket_edges block
#define CAP 3072       // max edges per bucket (mean 2048, sd ~45 -> +22 sigma)

typedef __attribute__((ext_vector_type(8))) short bf16x8v;
typedef __attribute__((ext_vector_type(4))) float f32x4;

__device__ __forceinline__ unsigned f2bf_bits(float f) {
    unsigned u = __float_as_uint(f);
    return (u + 0x7fffu + ((u >> 16) & 1u)) >> 16;   // RNE fp32 -> bf16 bits
}
__device__ __forceinline__ float bflo(unsigned u) { return __uint_as_float(u << 16); }
__device__ __forceinline__ float bfhi(unsigned u) { return __uint_as_float(u & 0xffff0000u); }

// ---------------------------------------------------------------------------
// MFMA GEMM: [h | as | ad] = bf16(x) @ B[128,144], fp32 acc.
// Block: 256 thr = 4 waves, 64 rows. Wave: 16 rows x 144 cols = 9 MFMA tiles.
// ---------------------------------------------------------------------------
__global__ __launch_bounds__(256) void gemm_mfma(const float* __restrict__ x,
                                                 const short* __restrict__ WtE,
                                                 short* __restrict__ hout,
                                                 float* __restrict__ as,
                                                 float* __restrict__ ad, int N) {
    __shared__ short xs[64 * 136];
    __shared__ short wt[144 * 136];
    const int tid = threadIdx.x;
    const int r0 = blockIdx.x * 64;

#pragma unroll
    for (int p = 0; p < 9; ++p) {
        int idx = p * 256 + tid;           // 2304 chunks of 8 shorts
        int n = idx >> 4, kk = (idx & 15) * 8;
        *(uint4*)&wt[n * 136 + kk] = *(const uint4*)(WtE + n * 128 + kk);
    }
#pragma unroll
    for (int p = 0; p < 8; ++p) {
        int lin = p * 1024 + tid * 4;
        int row = lin >> 7, k = lin & 127;
        int gr = r0 + row;
        int grc = gr < N ? gr : N - 1;
        float4 v = *(const float4*)(x + (size_t)grc * 128 + k);
        unsigned p0 = f2bf_bits(v.x) | (f2bf_bits(v.y) << 16);
        unsigned p1 = f2bf_bits(v.z) | (f2bf_bits(v.w) << 16);
        *(uint2*)&xs[row * 136 + k] = make_uint2(p0, p1);
    }
    __syncthreads();

    const int wv = tid >> 6;
    const int lane = tid & 63;
    const int lc = lane & 15, quad = lane >> 4;
    f32x4 acc[9];
#pragma unroll
    for (int c = 0; c < 9; ++c) acc[c] = (f32x4){0.f, 0.f, 0.f, 0.f};
    const short* aB = &xs[(wv * 16 + lc) * 136 + quad * 8];
    const short* bB = &wt[lc * 136 + quad * 8];
#pragma unroll
    for (int kc = 0; kc < 4; ++kc) {
        bf16x8v af = *(const bf16x8v*)(aB + kc * 32);
#pragma unroll
        for (int c = 0; c < 9; ++c) {
            bf16x8v bf = *(const bf16x8v*)(bB + c * (16 * 136) + kc * 32);
            acc[c] = __builtin_amdgcn_mfma_f32_16x16x32_bf16(af, bf, acc[c], 0, 0, 0);
        }
    }

    const int rowb = r0 + wv * 16 + quad * 4;
#pragma unroll
    for (int c = 0; c < 8; ++c) {
#pragma unroll
        for (int r = 0; r < 4; ++r) {
            int row = rowb + r;
            if (row < N) hout[(size_t)row * 128 + c * 16 + lc] = (short)f2bf_bits(acc[c][r]);
        }
    }
    // alpha columns: lc<8 -> as head lc; lc>=8 -> ad head lc-8
#pragma unroll
    for (int r = 0; r < 4; ++r) {
        int row = rowb + r;
        if (row < N) {
            if (lc < 8) as[row * 8 + lc] = acc[8][r];
            else        ad[row * 8 + (lc - 8)] = acc[8][r];
        }
    }
}

// ---------------------------------------------------------------------------
// Phase A: bucket edges by dst>>7 into per-block slabs. Register staging,
// packed uint32 = src | (dst&127)<<17. Hierarchical shfl scan.
// Blocks [0,nblk): bucketing. Blocks [nblk, nblk+18): absorbed prep_w work.
// ---------------------------------------------------------------------------
__global__ __launch_bounds__(1024) void bucket_edges(const int* __restrict__ ei, int E,
                                                     int nblk,
                                                     unsigned* __restrict__ slab,
                                                     int2* __restrict__ csG,
                                                     const float* __restrict__ W,
                                                     const float* __restrict__ a_src,
                                                     const float* __restrict__ a_dst,
                                                     short* __restrict__ WtE) {
    const int t = threadIdx.x;
    const int blk = blockIdx.x;

    if (blk >= nblk) {            // ---- prep_w path: 18 blocks x 1024 = 18432
        int id = (blk - nblk) * 1024 + t;
        if (id < 144 * 128) {
            int n = id >> 7, k = id & 127;
            float v;
            if (n < 128) {
                v = W[k * 128 + n];
            } else if (n < 136) {
                int hh = n - 128; float s = 0.f;
#pragma unroll
                for (int d = 0; d < 16; ++d) s += W[k * 128 + hh * 16 + d] * a_src[hh * 16 + d];
                v = s;
            } else {
                int hh = n - 136; float s = 0.f;
#pragma unroll
                for (int d = 0; d < 16; ++d) s += W[k * 128 + hh * 16 + d] * a_dst[hh * 16 + d];
                v = s;
            }
            WtE[id] = (short)f2bf_bits(v);
        }
        return;
    }

    __shared__ int hist[1024];
    __shared__ int cur[NBUCK];
    __shared__ int wpart[16];
    const int base = blk * ABLK;
    int count = E - base; if (count > ABLK) count = ABLK;

    int sr[8], dr[8];
    hist[t] = 0;
#pragma unroll
    for (int k = 0; k < 8; ++k) {
        int i = k * 1024 + t;
        if (i < count) { sr[k] = ei[base + i]; dr[k] = ei[E + base + i]; }
    }
    __syncthreads();
#pragma unroll
    for (int k = 0; k < 8; ++k) {
        int i = k * 1024 + t;
        if (i < count) atomicAdd(&hist[dr[k] >> 7], 1);
    }
    __syncthreads();
    int v = hist[t];
    int lane = t & 63, wid = t >> 6;
    int sc = v;
#pragma unroll
    for (int off = 1; off < 64; off <<= 1) { int u = __shfl_up(sc, off); if (lane >= off) sc += u; }
    if (lane == 63) wpart[wid] = sc;
    __syncthreads();
    if (wid == 0 && lane < 16) {
        int wv = wpart[lane], wsum = wv;
#pragma unroll
        for (int off = 1; off < 16; off <<= 1) { int u = __shfl_up(wsum, off); if (lane >= off) wsum += u; }
        wpart[lane] = wsum - wv;
    }
    __syncthreads();
    int excl = sc - v + wpart[wid];
    if (t < NBUCK) {
        csG[(size_t)blk * NBUCK + t] = make_int2(v, excl);
        cur[t] = excl;
    }
    __syncthreads();
#pragma unroll
    for (int k = 0; k < 8; ++k) {
        int i = k * 1024 + t;
        if (i < count) {
            int d = dr[k];
            int pos = atomicAdd(&cur[d >> 7], 1);
            slab[(size_t)blk * ABLK + pos] = (unsigned)sr[k] | ((unsigned)(d & 127) << 17);
        }
    }
}

// ---------------------------------------------------------------------------
// Phase B: per bucket of 128 dst nodes. 8-lane-group-per-segment LDS gather,
// hist + scan -> rowS/rowE (fixed CAP region per bucket), scatter sortedSrc.
// ---------------------------------------------------------------------------
__global__ __launch_bounds__(512) void build_csr(const unsigned* __restrict__ slab,
                                                 const int2* __restrict__ csG,
                                                 int nblk, int N,
                                                 int* __restrict__ rowS,
                                                 int* __restrict__ rowE,
                                                 int* __restrict__ sortedSrc) {
    __shared__ int eL[CAP];
    __shared__ int incl[512];
    __shared__ int cS[512];
    __shared__ int stS[512];
    __shared__ int lp[128];
    __shared__ int wpart[8];
    __shared__ int halfSum;
    const int bb = blockIdx.x;
    const int t = threadIdx.x;
    const int nodeBase = bb << 7;
    const int bBase = bb * CAP;

    int c = 0, st = 0;
    if (t < nblk) { int2 cs = csG[(size_t)t * NBUCK + bb]; c = cs.x; st = cs.y; }
    cS[t] = c; stS[t] = st;
    if (t < 128) lp[t] = 0;
    int lane = t & 63, wid = t >> 6;
    int sc = c;
#pragma unroll
    for (int off = 1; off < 64; off <<= 1) { int u = __shfl_up(sc, off); if (lane >= off) sc += u; }
    if (lane == 63) wpart[wid] = sc;
    __syncthreads();
    if (wid == 0 && lane < 8) {
        int wv = wpart[lane], wsum = wv;
#pragma unroll
        for (int off = 1; off < 8; off <<= 1) { int u = __shfl_up(wsum, off); if (lane >= off) wsum += u; }
        wpart[lane] = wsum - wv;
    }
    __syncthreads();
    incl[t] = sc + wpart[wid];
    __syncthreads();
    int total = incl[511];
    if (total > CAP) total = CAP;   // statically impossible; guards LDS OOB
    // 8-lane-group-per-segment gather: group g handles segments g, g+64, ...
    {
        const int grp = t >> 3, li = t & 7;
        for (int s = grp; s < nblk; s += 64) {
            int cc = cS[s];
            int off0 = incl[s] - cc;
            const unsigned* p = slab + (size_t)s * ABLK + stS[s];
            for (int i = li; i < cc; i += 8) eL[off0 + i] = (int)p[i];
        }
    }
    __syncthreads();
    for (int e = t; e < total; e += 512) atomicAdd(&lp[((unsigned)eL[e]) >> 17], 1);
    __syncthreads();
    // scan 128 node counts
    int cnt = 0, s2 = 0;
    if (t < 128) {
        cnt = lp[t];
        s2 = cnt;
#pragma unroll
        for (int off = 1; off < 64; off <<= 1) { int u = __shfl_up(s2, off); if (lane >= off) s2 += u; }
        if (t == 63) halfSum = s2;
    }
    __syncthreads();
    if (t < 128) {
        int inc2 = s2 + (t >= 64 ? halfSum : 0);
        int ex = inc2 - cnt;
        int gn = nodeBase + t;
        if (gn < N) { rowS[gn] = bBase + ex; rowE[gn] = bBase + ex + cnt; }
        lp[t] = ex;
    }
    __syncthreads();
    for (int e = t; e < total; e += 512) {
        unsigned pk = (unsigned)eL[e];
        int pos = atomicAdd(&lp[pk >> 17], 1);
        sortedSrc[bBase + pos] = (int)(pk & 0x1FFFFu);
    }
}

// ---------------------------------------------------------------------------
// Aggregate v5: one wave per dst node; lane = channel-pair.
//   Lane l owns output channels 2l,2l+1 (head = l>>3). Per edge: each lane
//   loads one dword of the h row (coalesced 256B/edge, same as v1) and FMAs
//   into a private f32x2. dsum is per-lane (8 lanes of a head compute the
//   same w) -> ZERO cross-lane reduction, zero DS ops (v1 paid ~150
//   inst/node of butterfly), one epilogue per wave.
//   Edge indices: 8/round via one 32B broadcast load, converted to SGPRs
//   with readlane -> per-edge addressing is SALU, and the round's 16 as/h
//   loads issue back-to-back (16 outstanding/wave; indices prefetched one
//   round ahead). Unlike v4, edges are NOT latency-serialized.
//   ~9 VALU/edge vs v1's ~37 wave-inst/edge.
// ---------------------------------------------------------------------------
__global__ __launch_bounds__(256, 8) void aggregate(const int* __restrict__ rowS,
                                                    const int* __restrict__ rowE,
                                                    const int* __restrict__ sortedSrc,
                                                    const short* __restrict__ h,
                                                    const float* __restrict__ as,
                                                    const float* __restrict__ ad,
                                                    const float* __restrict__ bias,
                                                    float* __restrict__ out, int N) {
    const int lane = threadIdx.x & 63;
    const int wv = threadIdx.x >> 6;
    const int node = __builtin_amdgcn_readfirstlane(blockIdx.x * 4 + wv);
    if (node >= N) return;
    const int p = lane >> 3;                 // head of this lane's channels
    const int start = __builtin_amdgcn_readfirstlane(rowS[node]);
    const int end   = __builtin_amdgcn_readfirstlane(rowE[node]);
    const float adv = ad[node * 8 + p];

    float accx = 0.f, accy = 0.f;
    float dsum = 0.f;

    int e = start;
    int iv = node;                            // safe default index
    { int q = e + (lane & 7); if (q < end) iv = sortedSrc[q]; }

    while (e < end) {
        float asv[8]; unsigned hwv[8];
#pragma unroll
        for (int k = 0; k < 8; ++k) {
            int j = __builtin_amdgcn_readlane(iv, k);     // SGPR edge src
            asv[k] = as[j * 8 + p];
            hwv[k] = *(const unsigned*)(h + (size_t)j * 128 + lane * 2);
        }
        int en = e + 8;
        int iv2 = node;
        { int q = en + (lane & 7); if (q < end) iv2 = sortedSrc[q]; }
#pragma unroll
        for (int k = 0; k < 8; ++k) {
            if (e + k < end) {                // scalar branch (e,end uniform)
                float tt = asv[k] + adv;
                tt = tt > 0.f ? tt : NEG_SLOPE * tt;
                float w = __expf(tt);
                unsigned u = hwv[k];
                accx += w * bflo(u);
                accy += w * bfhi(u);
                dsum += w;
            }
        }
        iv = iv2; e = en;
    }

    // self-loop
    {
        float tt = as[node * 8 + p] + adv;
        tt = tt > 0.f ? tt : NEG_SLOPE * tt;
        float w = __expf(tt);
        unsigned u = *(const unsigned*)(h + (size_t)node * 128 + lane * 2);
        accx += w * bflo(u);
        accy += w * bfhi(u);
        dsum += w;
    }

    float inv = 1.0f / (dsum + 1e-16f);
    float2 bv = *(const float2*)(bias + lane * 2);
    float o0 = accx * inv + bv.x;
    float o1 = accy * inv + bv.y;
    o0 = o0 > 0.f ? o0 : 0.f;
    o1 = o1 > 0.f ? o1 : 0.f;
    *(float2*)(out + (size_t)node * 128 + lane * 2) = make_float2(o0, o1);
}

extern "C" void kernel_launch(void* const* d_in, const int* in_sizes, int n_in,
                              void* d_out, int out_size, void* d_ws, size_t ws_size,
                              hipStream_t stream) {
    const float* x     = (const float*)d_in[0];
    const int*   ei    = (const int*)d_in[1];
    const float* W     = (const float*)d_in[2];
    const float* a_src = (const float*)d_in[3];
    const float* a_dst = (const float*)d_in[4];
    const float* bias  = (const float*)d_in[5];
    float* out = (float*)d_out;

    const int N = in_sizes[0] / 128;   // 100000
    const int E = in_sizes[1] / 2;     // 1600000
    const int nblk = (E + ABLK - 1) / ABLK;  // 196

    char* ws = (char*)d_ws;
    size_t off = 0;
    auto alloc = [&](size_t bytes) { void* p = ws + off; off = (off + bytes + 255) & ~(size_t)255; return p; };
    short*    h         = (short*)alloc((size_t)N * 128 * 2);
    float*    as        = (float*)alloc((size_t)N * 8 * 4);
    float*    ad        = (float*)alloc((size_t)N * 8 * 4);
    unsigned* slab      = (unsigned*)alloc((size_t)nblk * ABLK * 4);
    int2*     csG       = (int2*)alloc((size_t)nblk * NBUCK * 8);
    int*      sortedSrc = (int*)alloc((size_t)NBUCK * CAP * 4);
    int*      rowS      = (int*)alloc((size_t)N * 4);
    int*      rowE      = (int*)alloc((size_t)N * 4);
    short*    WtE       = (short*)alloc((size_t)144 * 128 * 2);

    bucket_edges<<<nblk + 18, 1024, 0, stream>>>(ei, E, nblk, slab, csG, W, a_src, a_dst, WtE);
    gemm_mfma<<<(N + 63) / 64, 256, 0, stream>>>(x, WtE, h, as, ad, N);
    build_csr<<<NBUCK, 512, 0, stream>>>(slab, csG, nblk, N, rowS, rowE, sortedSrc);
    aggregate<<<(N + 3) / 4, 256, 0, stream>>>(rowS, rowE, sortedSrc, h, as, ad, bias, out, N);
}